// Round 1
// baseline (622.025 us; speedup 1.0000x reference)
//
#include <hip/hip_runtime.h>
#include <stdint.h>
#include <stddef.h>

// ---------------------------------------------------------------------------
// out[b,t,f] = x @ (w + 2.0 * lora_a @ lora_b)     (LoRA folded into weight)
// M = 8192 (B*T), K = 2048 (D), N = 8192 (F). fp32 in/out, bf16 MFMA compute.
// ---------------------------------------------------------------------------

typedef __bf16 bf16;
typedef __bf16 bf16x4 __attribute__((ext_vector_type(4)));
typedef __bf16 bf16x8 __attribute__((ext_vector_type(8)));
typedef float  f32x4  __attribute__((ext_vector_type(4)));

#define M_DIM 8192
#define N_DIM 8192
#define K_DIM 2048
#define LRANK 16
#define LSCALE 2.0f

#define BM 128
#define BN 128
#define BK 64

typedef __attribute__((address_space(1))) void* as1_void;
typedef __attribute__((address_space(3))) void* as3_void;

__device__ __forceinline__ void gload_lds16(const void* g, void* l) {
    // async global->LDS, 16 bytes per lane; LDS dst must be wave-uniform
    // base + lane*16 (it is: callers pass base + tid*16 within each wave).
    __builtin_amdgcn_global_load_lds((as1_void)(g), (as3_void)(l), 16, 0, 0);
}

// ---------------------------------------------------------------------------
// Kernel 1: x fp32 -> bf16, straight convert. 4 elems/thread.
// ---------------------------------------------------------------------------
__global__ void convert_x_kernel(const float* __restrict__ x,
                                 bf16* __restrict__ xb) {
    int i = (blockIdx.x * blockDim.x + threadIdx.x) * 4;
    float4 v = *(const float4*)(x + i);
    bf16x4 o;
    o.x = (bf16)v.x; o.y = (bf16)v.y; o.z = (bf16)v.z; o.w = (bf16)v.w;
    *(bf16x4*)(xb + i) = o;
}

// ---------------------------------------------------------------------------
// Kernel 2: Wt[n][k] = bf16( w[k][n] + 2.0 * sum_L a[k][L]*b[L][n] )
// 32x32 tile transpose through LDS; coalesced loads AND stores.
// ---------------------------------------------------------------------------
__global__ void fold_transpose_kernel(const float* __restrict__ w,   // [K][N]
                                      const float* __restrict__ la,  // [K][16]
                                      const float* __restrict__ lb,  // [16][N]
                                      bf16* __restrict__ wt) {       // [N][K]
    __shared__ float tile[32][33];   // +1 pad: conflict-free transpose read
    __shared__ float at[32][17];     // a rows for this k-block (+1 pad)
    __shared__ float bt[16][32];     // b cols for this n-block

    const int k0 = blockIdx.x * 32;
    const int n0 = blockIdx.y * 32;
    const int t  = threadIdx.x;      // 256 threads
    const int c  = t & 31;
    const int r0 = t >> 5;           // 0..7

    // load w tile (coalesced: 32 consecutive floats per row)
    #pragma unroll
    for (int rr = 0; rr < 32; rr += 8)
        tile[r0 + rr][c] = w[(size_t)(k0 + r0 + rr) * N_DIM + n0 + c];

    // load a rows: 32x16 = 512 floats, 2 per thread
    at[t >> 4][t & 15]          = la[(size_t)(k0 + (t >> 4)) * LRANK + (t & 15)];
    at[(t + 256) >> 4][t & 15]  = la[(size_t)(k0 + ((t + 256) >> 4)) * LRANK + (t & 15)];

    // load b cols: 16x32 = 512 floats, 2 per thread
    bt[t >> 5][c]       = lb[(size_t)(t >> 5) * N_DIM + n0 + c];
    bt[(t >> 5) + 8][c] = lb[(size_t)((t >> 5) + 8) * N_DIM + n0 + c];

    __syncthreads();

    // write transposed (coalesced along K): thread -> (k_local=c, n_local=r0+rr)
    #pragma unroll
    for (int rr = 0; rr < 32; rr += 8) {
        const int nl = r0 + rr;
        const int kl = c;
        float delta = 0.f;
        #pragma unroll
        for (int L = 0; L < LRANK; ++L)
            delta += at[kl][L] * bt[L][nl];
        float v = tile[kl][nl] + LSCALE * delta;
        wt[(size_t)(n0 + nl) * K_DIM + k0 + kl] = (bf16)v;
    }
}

// ---------------------------------------------------------------------------
// Kernel 3: C[M][N] = A[M][K] * Bt[N][K]^T, bf16 inputs, fp32 out.
// m97 structure: 128x128 tile, BK=64, 4 waves (each 64x64 = 4x4 MFMA tiles),
// global_load_lds width-16 staging, XOR-swizzled LDS (16B chunk ^= row&7).
// ---------------------------------------------------------------------------
__global__ __launch_bounds__(256)
void gemm_bf16_kernel(const bf16* __restrict__ A,   // [M][K]
                      const bf16* __restrict__ Bt,  // [N][K]
                      float* __restrict__ C) {      // [M][N]
    // 128 rows x 64 cols bf16 = 16 KB each. Row = 128 B = 8 chunks of 16 B.
    __shared__ __align__(16) bf16 As[BM * BK];
    __shared__ __align__(16) bf16 Bs[BN * BK];

    const int t    = threadIdx.x;
    const int lane = t & 63;
    const int wave = t >> 6;            // 0..3
    const int wm   = (wave >> 1) * 64;  // wave row offset inside tile
    const int wn   = (wave & 1) * 64;

    const int n0 = blockIdx.x * BN;
    const int m0 = blockIdx.y * BM;

    // staging descriptors: 4 calls of 16B/thread cover 16 KB.
    // physical chunk cp at (row, cp) holds logical k-chunk cl = cp ^ (row&7).
    int rowS[4], clS[4];
    #pragma unroll
    for (int j = 0; j < 4; ++j) {
        int p   = j * 4096 + t * 16;      // physical byte pos in tile
        int row = p >> 7;                  // 128 B per row
        int cp  = (p >> 4) & 7;
        rowS[j] = row;
        clS[j]  = cp ^ (row & 7);
    }
    const bf16* aBase = A  + (size_t)m0 * K_DIM;
    const bf16* bBase = Bt + (size_t)n0 * K_DIM;

    // fragment read offsets (bf16 elems), loop-invariant over K
    int offA[2][4], offB[2][4];
    #pragma unroll
    for (int ks = 0; ks < 2; ++ks) {
        #pragma unroll
        for (int i = 0; i < 4; ++i) {
            int rowa = wm + i * 16 + (lane & 15);
            int rowb = wn + i * 16 + (lane & 15);
            int cl   = ks * 4 + (lane >> 4);
            offA[ks][i] = rowa * 64 + ((cl ^ (rowa & 7)) * 8);
            offB[ks][i] = rowb * 64 + ((cl ^ (rowb & 7)) * 8);
        }
    }

    f32x4 acc[4][4] = {};

    for (int kt = 0; kt < K_DIM / BK; ++kt) {
        const int k0 = kt * BK;
        #pragma unroll
        for (int j = 0; j < 4; ++j) {
            gload_lds16(aBase + (size_t)rowS[j] * K_DIM + k0 + clS[j] * 8,
                        As + j * 2048 + t * 8);
            gload_lds16(bBase + (size_t)rowS[j] * K_DIM + k0 + clS[j] * 8,
                        Bs + j * 2048 + t * 8);
        }
        __syncthreads();   // compiler emits vmcnt(0) drain before barrier

        #pragma unroll
        for (int ks = 0; ks < 2; ++ks) {
            bf16x8 af[4], bfr[4];
            #pragma unroll
            for (int i = 0; i < 4; ++i) af[i]  = *(const bf16x8*)(As + offA[ks][i]);
            #pragma unroll
            for (int i = 0; i < 4; ++i) bfr[i] = *(const bf16x8*)(Bs + offB[ks][i]);
            #pragma unroll
            for (int mi = 0; mi < 4; ++mi)
                #pragma unroll
                for (int ni = 0; ni < 4; ++ni)
                    acc[mi][ni] = __builtin_amdgcn_mfma_f32_16x16x32_bf16(
                        af[mi], bfr[ni], acc[mi][ni], 0, 0, 0);
        }
        __syncthreads();
    }

    // epilogue: C/D layout col = lane&15, row = (lane>>4)*4 + reg
    const int cr = (lane >> 4) * 4;
    const int cc = lane & 15;
    float* cBase = C + (size_t)(m0 + wm + cr) * N_DIM + (n0 + wn + cc);
    #pragma unroll
    for (int mi = 0; mi < 4; ++mi)
        #pragma unroll
        for (int r = 0; r < 4; ++r)
            #pragma unroll
            for (int ni = 0; ni < 4; ++ni)
                cBase[(size_t)(mi * 16 + r) * N_DIM + ni * 16] = acc[mi][ni][r];
}

// ---------------------------------------------------------------------------
extern "C" void kernel_launch(void* const* d_in, const int* in_sizes, int n_in,
                              void* d_out, int out_size, void* d_ws, size_t ws_size,
                              hipStream_t stream) {
    const float* x  = (const float*)d_in[0];   // [B,T,D] = [8192, 2048]
    const float* w  = (const float*)d_in[1];   // [D, F]  = [2048, 8192]
    const float* la = (const float*)d_in[2];   // [D, 16]
    const float* lb = (const float*)d_in[3];   // [16, F]
    float* out = (float*)d_out;                // [8192, 8192]

    bf16* xb = (bf16*)d_ws;                                        // 32 MB
    bf16* wt = (bf16*)((char*)d_ws + (size_t)M_DIM * K_DIM * 2);   // 32 MB

    convert_x_kernel<<<M_DIM * K_DIM / 4 / 256, 256, 0, stream>>>(x, xb);
    fold_transpose_kernel<<<dim3(K_DIM / 32, N_DIM / 32), 256, 0, stream>>>(w, la, lb, wt);
    gemm_bf16_kernel<<<dim3(N_DIM / BN, M_DIM / BM), 256, 0, stream>>>(xb, wt, out);
}